// Round 5
// baseline (365.033 us; speedup 1.0000x reference)
//
#include <hip/hip_runtime.h>
#include <cstdint>
#include <cstddef>

typedef _Float16 f16;
typedef _Float16 half4 __attribute__((ext_vector_type(4)));
typedef _Float16 half8 __attribute__((ext_vector_type(8)));
typedef float f32x16 __attribute__((ext_vector_type(16)));

#define BN_EPS 1e-5f

// ---------------- workspace layout (bytes) ----------------
static constexpr size_t OFF_XB  = 0;          // f16 [64][32][32][256] NHWC      33,554,432
static constexpr size_t OFF_ZB  = 33554432;   // f16 [64][16][16][256] NHWC       8,388,608
static constexpr size_t OFF_WX  = 41943040;   // f16 [9][256][256]                1,179,648
static constexpr size_t OFF_WZ  = 43122688;   // f16 [9][256][256]                1,179,648
static constexpr size_t OFF_BNX = 44302336;   // f32 scale[256], bias[256]            2,048
static constexpr size_t OFF_BNZ = 44304384;   //                                      2,048
static constexpr size_t OFF_XFH = 44306432;   // f16 [16384][30][32]             31,457,280
static constexpr size_t OFF_ZFH = 75763712;   // f16 [16384][14][16]              7,340,032

// ---------------- fused prep: transposes + weight repack + BN fold ----------------
__global__ __launch_bounds__(256) void prep_all(
    const float* __restrict__ x, const float* __restrict__ z,
    const float* __restrict__ w_x, const float* __restrict__ w_z,
    const float* __restrict__ gx, const float* __restrict__ bx,
    const float* __restrict__ mx, const float* __restrict__ vx,
    const float* __restrict__ gz, const float* __restrict__ bz,
    const float* __restrict__ mz, const float* __restrict__ vz,
    f16* __restrict__ xb, f16* __restrict__ zb,
    f16* __restrict__ wxA, f16* __restrict__ wzA,
    float* __restrict__ bnx, float* __restrict__ bnz) {
  __shared__ float tile[64][33];
  const int bid = blockIdx.x;
  const int tid = threadIdx.x;
  if (bid < 12288) {
    const float* src; f16* dst; int lw, r;
    if (bid < 8192) { src = x; dst = xb; lw = 5; r = bid; }
    else            { src = z; dst = zb; lw = 4; r = bid - 8192; }
    const int W = 1 << lw;
    const int c0 = (r & 3) << 6;
    const int h = (r >> 2) & (W - 1);
    const int b = (r >> 2) >> lw;
    const float* sp = src + (size_t)(((b << 8) + c0) << lw << lw) + ((size_t)h << lw);
    const int n = W << 6;
    for (int i = tid; i < n; i += 256) {
      int cl = i >> lw, w = i & (W - 1);
      tile[cl][w] = sp[(size_t)cl << lw << lw | w];
    }
    __syncthreads();
    f16* dp = dst + ((size_t)((b << lw) + h) << lw << 8) + c0;
    for (int i = tid; i < n; i += 256) {
      int w = i >> 6, cl = i & 63;
      dp[(w << 8) + cl] = (f16)tile[cl][w];
    }
  } else if (bid < 16896) {
    int r = bid - 12288;
    const float* src = (r < 2304) ? w_x : w_z;
    f16* dst = (r < 2304) ? wxA : wzA;
    int rr = (r < 2304) ? r : r - 2304;
    int idx = rr * 256 + tid;
    int cin = idx & 255, cout = (idx >> 8) & 255, khw = idx >> 16;
    dst[idx] = (f16)src[(cout * 256 + cin) * 9 + khw];
  } else {
    int c = tid;
    float iv = gx[c] / sqrtf(vx[c] + BN_EPS);
    bnx[c] = iv;
    bnx[256 + c] = bx[c] - mx[c] * iv;
    float iz = gz[c] / sqrtf(vz[c] + BN_EPS);
    bnz[c] = iz;
    bnz[256 + c] = bz[c] - mz[c] * iz;
  }
}

// ---------------- conv3x3 + BN, v2: M=256 x N=64 blocks, 32x32x16 MFMA ----------------
__device__ __forceinline__ void gl_lds16(const f16* g, f16* l) {
  __builtin_amdgcn_global_load_lds((__attribute__((address_space(1))) void*)g,
                                   (__attribute__((address_space(3))) void*)l, 16, 0, 0);
}

// blocks 0..899: conv_x (nblk = bid); 900..1095: conv_z (nblk = bid-900)
__global__ __launch_bounds__(128, 2) void conv_gemm_v2(
    const f16* __restrict__ xb, const f16* __restrict__ zb,
    const f16* __restrict__ wx, const f16* __restrict__ wz,
    const float* __restrict__ bnx, const float* __restrict__ bnz,
    f16* __restrict__ xfh, f16* __restrict__ zfh) {
  __shared__ f16 As[256 * 64];  // [cout][k64] rows of 128B, XOR-swizzled 16B chunks
  __shared__ f16 Bs[64 * 64];   // [pixel][k64]
  const int bid = blockIdx.x;
  const f16* inp; const f16* wA; const float* bn; f16* out;
  int nblk, HIN, WIN, WOUT, NPIX, WPAD, OPLANE;
  if (bid < 900) {
    inp = xb; wA = wx; bn = bnx; out = xfh; nblk = bid;
    HIN = 32; WIN = 32; WOUT = 30; NPIX = 900; WPAD = 32; OPLANE = 960;
  } else {
    inp = zb; wA = wz; bn = bnz; out = zfh; nblk = bid - 900;
    HIN = 16; WIN = 16; WOUT = 14; NPIX = 196; WPAD = 16; OPLANE = 224;
  }
  const int t = threadIdx.x;
  const int w = t >> 6;              // wave 0/1 -> couts [0,128) / [128,256)
  const int L = t & 63;
  const int rbase = (w << 3) + (L >> 3);              // 0..15
  const int swz = (((L & 7) ^ (rbase & 7)) << 3);     // fixed per-lane chunk swizzle (halves)
  const int abase = (rbase << 8) + swz;               // A row stride = 256 halves

  // B pixel global bases (4 staging issues per wave, rows p = l*16 + rbase)
  int ib[4];
#pragma unroll
  for (int l = 0; l < 4; ++l) {
    int p = (l << 4) + rbase;
    int n = (nblk << 6) + p;
    int b = n / NPIX, rem = n - b * NPIX;
    int oh = rem / WOUT, ow = rem - oh * WOUT;
    ib[l] = (((b * HIN + oh) * WIN + ow) << 8) + swz;
  }

  f32x16 acc[4][2] = {};

  for (int kt = 0; kt < 36; ++kt) {
    // khw-innermost: same B rows re-read at 1-kt spacing -> L2-resident
    const int cinb = kt / 9;
    const int khw = kt - cinb * 9;
    const int kh = khw / 3, kw = khw - kh * 3;
    const int wofs = (khw << 16) + (cinb << 6);
    const int iofs = ((kh * WIN + kw) << 8) + (cinb << 6);
    // stage A: 256 rows -> 16 issues/wave (rows l*16 + w*8 + lane/8)
#pragma unroll
    for (int l = 0; l < 16; ++l)
      gl_lds16(wA + wofs + (l << 12) + abase, As + ((((l << 4) + (w << 3))) << 6));
    // stage B: 64 rows -> 4 issues/wave
#pragma unroll
    for (int l = 0; l < 4; ++l)
      gl_lds16(inp + iofs + ib[l], Bs + ((((l << 4) + (w << 3))) << 6));
    __syncthreads();

#pragma unroll
    for (int ks = 0; ks < 4; ++ks) {
      const int ch = ((((ks << 1) + (L >> 5)) ^ (L & 7)) << 3);
      half8 af[4], bf[2];
#pragma unroll
      for (int mt = 0; mt < 4; ++mt)
        af[mt] = *(const half8*)&As[(((w << 7) + (mt << 5) + (L & 31)) << 6) + ch];
#pragma unroll
      for (int nt = 0; nt < 2; ++nt)
        bf[nt] = *(const half8*)&Bs[(((nt << 5) + (L & 31)) << 6) + ch];
#pragma unroll
      for (int mt = 0; mt < 4; ++mt)
#pragma unroll
        for (int nt = 0; nt < 2; ++nt)
          acc[mt][nt] =
              __builtin_amdgcn_mfma_f32_32x32x16_f16(af[mt], bf[nt], acc[mt][nt], 0, 0, 0);
    }
    __syncthreads();
  }

  // epilogue: BN + f16 padded store.
  // 32x32 C/D layout: col = lane&31, row = (reg&3) + 8*(reg>>2) + 4*(lane>>5)
#pragma unroll
  for (int nt = 0; nt < 2; ++nt) {
    int n_g = (nblk << 6) + (nt << 5) + (L & 31);
    int b = n_g / NPIX, rem = n_g - b * NPIX;
    int oh = rem / WOUT, ow = rem - oh * WOUT;
    f16* op = out + (size_t)(b << 8) * OPLANE + oh * WPAD + ow;
#pragma unroll
    for (int mt = 0; mt < 4; ++mt) {
      const int mb = (w << 7) + (mt << 5) + ((L >> 5) << 2);
#pragma unroll
      for (int rg = 0; rg < 16; ++rg) {
        int m = mb + (rg & 3) + ((rg >> 2) << 3);
        op[(size_t)m * OPLANE] = (f16)(acc[mt][nt][rg] * bn[m] + bn[256 + m]);
      }
    }
  }
}

// ---------------- depthwise xcorr v3 (unchanged) ----------------
static constexpr int XST = 40;
static constexpr int XCH = 30 * XST;
static constexpr int ZCH = 14 * 16;

__global__ __launch_bounds__(256) void xcorr_dw3(const f16* __restrict__ zfh,
                                                 const f16* __restrict__ xfh,
                                                 float* __restrict__ out) {
  __shared__ f16 xs[3 * XCH];
  __shared__ f16 zs[3 * ZCH];
  const int t = threadIdx.x;
  const int ch0 = blockIdx.x * 3;

  for (int i = t; i < 360; i += 256) {
    int ch = i / 120, rem = i - ch * 120;
    int row = rem >> 2, col = (rem & 3) << 3;
    if (ch0 + ch < 16384)
      *(half8*)(xs + ch * XCH + row * XST + col) =
          *(const half8*)(xfh + (size_t)(ch0 + ch) * 960 + row * 32 + col);
  }
  for (int i = t; i < 84; i += 256) {
    int ch = i / 28, rem = i - ch * 28;
    if (ch0 + ch < 16384)
      *(half8*)(zs + ch * ZCH + rem * 8) =
          *(const half8*)(zfh + (size_t)(ch0 + ch) * 224 + rem * 8);
  }
  __syncthreads();

  int lc = t / 85;
  int r = t - lc * 85;
  const bool ok = (lc < 3) && (ch0 + lc < 16384);
  if (lc > 2) lc = 2;
  const int oy = r / 5, oxq = r - oy * 5, ox0 = oxq * 4;
  const f16* xbp = xs + lc * XCH;
  const f16* zbp = zs + lc * ZCH;

  float acc[4] = {0.f, 0.f, 0.f, 0.f};

#pragma unroll 2
  for (int u = 0; u < 14; ++u) {
    float xr[20];
#pragma unroll
    for (int k = 0; k < 5; ++k) {
      half4 h = *(const half4*)(xbp + (oy + u) * XST + ox0 + k * 4);
#pragma unroll
      for (int e = 0; e < 4; ++e) xr[k * 4 + e] = (float)h[e];
    }
    float zc[14];
    {
      half8 z0 = *(const half8*)(zbp + u * 16);
      half8 z1 = *(const half8*)(zbp + u * 16 + 8);
#pragma unroll
      for (int e = 0; e < 8; ++e) zc[e] = (float)z0[e];
#pragma unroll
      for (int e = 0; e < 6; ++e) zc[8 + e] = (float)z1[e];
    }
#pragma unroll
    for (int v = 0; v < 14; ++v)
#pragma unroll
      for (int j = 0; j < 4; ++j) acc[j] = fmaf(zc[v], xr[v + j], acc[j]);
  }

  if (ok) {
    float* op = out + (size_t)(ch0 + lc) * 289 + oy * 17;
#pragma unroll
    for (int j = 0; j < 4; ++j) {
      int ox = ox0 + j;
      if (ox < 17) op[ox] = acc[j];
    }
  }
}

extern "C" void kernel_launch(void* const* d_in, const int* in_sizes, int n_in,
                              void* d_out, int out_size, void* d_ws, size_t ws_size,
                              hipStream_t stream) {
  const float* z = (const float*)d_in[0];
  const float* x = (const float*)d_in[1];
  const float* w_z = (const float*)d_in[2];
  const float* w_x = (const float*)d_in[3];
  const float* gamma_z = (const float*)d_in[4];
  const float* beta_z = (const float*)d_in[5];
  const float* mean_z = (const float*)d_in[6];
  const float* var_z = (const float*)d_in[7];
  const float* gamma_x = (const float*)d_in[8];
  const float* beta_x = (const float*)d_in[9];
  const float* mean_x = (const float*)d_in[10];
  const float* var_x = (const float*)d_in[11];

  char* ws = (char*)d_ws;
  f16* xb = (f16*)(ws + OFF_XB);
  f16* zb = (f16*)(ws + OFF_ZB);
  f16* wxA = (f16*)(ws + OFF_WX);
  f16* wzA = (f16*)(ws + OFF_WZ);
  float* bnx = (float*)(ws + OFF_BNX);
  float* bnz = (float*)(ws + OFF_BNZ);
  f16* xfh = (f16*)(ws + OFF_XFH);
  f16* zfh = (f16*)(ws + OFF_ZFH);
  float* out = (float*)d_out;

  prep_all<<<16897, 256, 0, stream>>>(x, z, w_x, w_z,
                                      gamma_x, beta_x, mean_x, var_x,
                                      gamma_z, beta_z, mean_z, var_z,
                                      xb, zb, wxA, wzA, bnx, bnz);

  conv_gemm_v2<<<1096, 128, 0, stream>>>(xb, zb, wxA, wzA, bnx, bnz, xfh, zfh);

  xcorr_dw3<<<(16384 + 2) / 3, 256, 0, stream>>>(zfh, xfh, out);
}

// Round 6
// 310.857 us; speedup vs baseline: 1.1743x; 1.1743x over previous
//
#include <hip/hip_runtime.h>
#include <cstdint>
#include <cstddef>

typedef _Float16 f16;
typedef _Float16 half4 __attribute__((ext_vector_type(4)));
typedef _Float16 half8 __attribute__((ext_vector_type(8)));
typedef float f32x4 __attribute__((ext_vector_type(4)));

#define BN_EPS 1e-5f

// ---------------- workspace layout (bytes) ----------------
static constexpr size_t OFF_XB  = 0;          // f16 [64][32][32][256] NHWC      33,554,432
static constexpr size_t OFF_ZB  = 33554432;   // f16 [64][16][16][256] NHWC       8,388,608
static constexpr size_t OFF_WX  = 41943040;   // f16 [9][256][256]                1,179,648
static constexpr size_t OFF_WZ  = 43122688;   // f16 [9][256][256]                1,179,648
static constexpr size_t OFF_BNX = 44302336;   // f32 scale[256], bias[256]            2,048
static constexpr size_t OFF_BNZ = 44304384;   //                                      2,048
static constexpr size_t OFF_XFH = 44306432;   // f16 [16384][30][32]             31,457,280
static constexpr size_t OFF_ZFH = 75763712;   // f16 [16384][14][16]              7,340,032

// ---------------- fused prep: transposes + weight repack + BN fold ----------------
__global__ __launch_bounds__(256) void prep_all(
    const float* __restrict__ x, const float* __restrict__ z,
    const float* __restrict__ w_x, const float* __restrict__ w_z,
    const float* __restrict__ gx, const float* __restrict__ bx,
    const float* __restrict__ mx, const float* __restrict__ vx,
    const float* __restrict__ gz, const float* __restrict__ bz,
    const float* __restrict__ mz, const float* __restrict__ vz,
    f16* __restrict__ xb, f16* __restrict__ zb,
    f16* __restrict__ wxA, f16* __restrict__ wzA,
    float* __restrict__ bnx, float* __restrict__ bnz) {
  __shared__ float tile[64][33];
  const int bid = blockIdx.x;
  const int tid = threadIdx.x;
  if (bid < 12288) {
    const float* src; f16* dst; int lw, r;
    if (bid < 8192) { src = x; dst = xb; lw = 5; r = bid; }
    else            { src = z; dst = zb; lw = 4; r = bid - 8192; }
    const int W = 1 << lw;
    const int c0 = (r & 3) << 6;
    const int h = (r >> 2) & (W - 1);
    const int b = (r >> 2) >> lw;
    const float* sp = src + (size_t)(((b << 8) + c0) << lw << lw) + ((size_t)h << lw);
    const int n = W << 6;
    for (int i = tid; i < n; i += 256) {
      int cl = i >> lw, w = i & (W - 1);
      tile[cl][w] = sp[(size_t)cl << lw << lw | w];
    }
    __syncthreads();
    f16* dp = dst + ((size_t)((b << lw) + h) << lw << 8) + c0;
    for (int i = tid; i < n; i += 256) {
      int w = i >> 6, cl = i & 63;
      dp[(w << 8) + cl] = (f16)tile[cl][w];
    }
  } else if (bid < 16896) {
    int r = bid - 12288;
    const float* src = (r < 2304) ? w_x : w_z;
    f16* dst = (r < 2304) ? wxA : wzA;
    int rr = (r < 2304) ? r : r - 2304;
    int idx = rr * 256 + tid;
    int cin = idx & 255, cout = (idx >> 8) & 255, khw = idx >> 16;
    dst[idx] = (f16)src[(cout * 256 + cin) * 9 + khw];
  } else {
    int c = tid;
    float iv = gx[c] / sqrtf(vx[c] + BN_EPS);
    bnx[c] = iv;
    bnx[256 + c] = bx[c] - mx[c] * iv;
    float iz = gz[c] / sqrtf(vz[c] + BN_EPS);
    bnz[c] = iz;
    bnz[256 + c] = bz[c] - mz[c] * iz;
  }
}

// ---------------- unified implicit-im2col conv3x3 + BN (MFMA f16), BK=64 ----------------
// Round-4 structure (256 thr / 4 waves / 128x128 tile / 0 conflicts) +
// khw-innermost kt order (L2-resident B re-reads) + XCD-paired mblk mapping.
__device__ __forceinline__ void gl_lds16(const f16* g, f16* l) {
  __builtin_amdgcn_global_load_lds((__attribute__((address_space(1))) void*)g,
                                   (__attribute__((address_space(3))) void*)l, 16, 0, 0);
}

__global__ __launch_bounds__(256, 4) void conv_gemm_u(
    const f16* __restrict__ xb, const f16* __restrict__ zb,
    const f16* __restrict__ wx, const f16* __restrict__ wz,
    const float* __restrict__ bnx, const float* __restrict__ bnz,
    f16* __restrict__ xfh, f16* __restrict__ zfh) {
  __shared__ f16 As[128 * 64];  // [cout_local][k64]  rows of 128B, XOR-swizzled 16B chunks
  __shared__ f16 Bs[128 * 64];  // [n_local][k64]
  // XCD pairing: blocks g and g+8 share (pair, xcd), differ in mblk -> same XCD
  const int g = blockIdx.x;
  const int pairIdx = ((g >> 4) << 3) | (g & 7);
  const int mblk = (g >> 3) & 1;
  if (pairIdx >= 548) return;
  const f16* inp; const f16* wA; const float* bn; f16* out;
  int nblk, HIN, WIN, WOUT, NPIX, WPAD, OPLANE;
  if (pairIdx < 450) {
    inp = xb; wA = wx; bn = bnx; out = xfh; nblk = pairIdx;
    HIN = 32; WIN = 32; WOUT = 30; NPIX = 900; WPAD = 32; OPLANE = 960;
  } else {
    inp = zb; wA = wz; bn = bnz; out = zfh; nblk = pairIdx - 450;
    HIN = 16; WIN = 16; WOUT = 14; NPIX = 196; WPAD = 16; OPLANE = 224;
  }
  const int tid = threadIdx.x;
  const int wid = tid >> 6, lane = tid & 63;
  const int wm = (wid >> 1) << 6, wn = (wid & 1) << 6;
  const int q = lane >> 4, lm = lane & 15;
  const int sr = lane >> 3, sc = lane & 7;   // staging: 8 rows x 8 chunks of 16B
  const int swz = (sc ^ sr) << 3;            // LDS slot sc holds global chunk sc^(row&7)
  const int mbase = mblk << 7;

  int arow[4], brow[4];
#pragma unroll
  for (int l = 0; l < 4; ++l) {
    int rr = (wid << 5) + (l << 3) + sr;
    arow[l] = ((mbase + rr) << 8) + swz;
    int n = (nblk << 7) + rr;
    int b = n / NPIX, rem = n - b * NPIX;
    int oh = rem / WOUT, ow = rem - oh * WOUT;
    brow[l] = (((b * HIN + oh) * WIN + ow) << 8) + swz;
  }

  f32x4 acc[4][4] = {};
  const int cA0 = (q ^ (lm & 7)) << 3;

  for (int kt = 0; kt < 36; ++kt) {
    // khw-innermost: B rows re-read at 1-kt spacing -> L2-resident
    const int cinb = kt / 9;
    const int khw = kt - cinb * 9;
    const int cin0 = cinb << 6;
    const int kh = khw / 3, kw = khw - kh * 3;
    const int wofs = (khw << 16) + cin0;
    const int iofs = ((kh * WIN + kw) << 8) + cin0;
#pragma unroll
    for (int l = 0; l < 4; ++l) {
      const int ldso = ((wid << 5) + (l << 3)) << 6;
      gl_lds16(wA + wofs + arow[l], As + ldso);
      gl_lds16(inp + iofs + brow[l], Bs + ldso);
    }
    __syncthreads();
#pragma unroll
    for (int h = 0; h < 2; ++h) {
      const int co = cA0 ^ (h << 5);
      half8 af[4], bf[4];
#pragma unroll
      for (int f = 0; f < 4; ++f) {
        af[f] = *(const half8*)&As[((wm + (f << 4) + lm) << 6) + co];
        bf[f] = *(const half8*)&Bs[((wn + (f << 4) + lm) << 6) + co];
      }
#pragma unroll
      for (int fm = 0; fm < 4; ++fm)
#pragma unroll
        for (int fn = 0; fn < 4; ++fn)
          acc[fm][fn] =
              __builtin_amdgcn_mfma_f32_16x16x32_f16(af[fm], bf[fn], acc[fm][fn], 0, 0, 0);
    }
    __syncthreads();
  }

  // epilogue: BN + f16 padded store. C/D: row m = q*4+reg, col n = lm.
#pragma unroll
  for (int fn = 0; fn < 4; ++fn) {
    int n_g = (nblk << 7) + wn + (fn << 4) + lm;
    int b = n_g / NPIX, rem = n_g - b * NPIX;
    int oh = rem / WOUT, ow = rem - oh * WOUT;
    f16* op = out + (size_t)(b << 8) * OPLANE + oh * WPAD + ow;
#pragma unroll
    for (int fm = 0; fm < 4; ++fm) {
      int m0 = mbase + wm + (fm << 4) + (q << 2);
#pragma unroll
      for (int rg = 0; rg < 4; ++rg) {
        int m = m0 + rg;
        op[(size_t)m * OPLANE] = (f16)(acc[fm][fn][rg] * bn[m] + bn[256 + m]);
      }
    }
  }
}

// ---------------- depthwise xcorr v3 (unchanged) ----------------
static constexpr int XST = 40;
static constexpr int XCH = 30 * XST;
static constexpr int ZCH = 14 * 16;

__global__ __launch_bounds__(256) void xcorr_dw3(const f16* __restrict__ zfh,
                                                 const f16* __restrict__ xfh,
                                                 float* __restrict__ out) {
  __shared__ f16 xs[3 * XCH];
  __shared__ f16 zs[3 * ZCH];
  const int t = threadIdx.x;
  const int ch0 = blockIdx.x * 3;

  for (int i = t; i < 360; i += 256) {
    int ch = i / 120, rem = i - ch * 120;
    int row = rem >> 2, col = (rem & 3) << 3;
    if (ch0 + ch < 16384)
      *(half8*)(xs + ch * XCH + row * XST + col) =
          *(const half8*)(xfh + (size_t)(ch0 + ch) * 960 + row * 32 + col);
  }
  for (int i = t; i < 84; i += 256) {
    int ch = i / 28, rem = i - ch * 28;
    if (ch0 + ch < 16384)
      *(half8*)(zs + ch * ZCH + rem * 8) =
          *(const half8*)(zfh + (size_t)(ch0 + ch) * 224 + rem * 8);
  }
  __syncthreads();

  int lc = t / 85;
  int r = t - lc * 85;
  const bool ok = (lc < 3) && (ch0 + lc < 16384);
  if (lc > 2) lc = 2;
  const int oy = r / 5, oxq = r - oy * 5, ox0 = oxq * 4;
  const f16* xbp = xs + lc * XCH;
  const f16* zbp = zs + lc * ZCH;

  float acc[4] = {0.f, 0.f, 0.f, 0.f};

#pragma unroll 2
  for (int u = 0; u < 14; ++u) {
    float xr[20];
#pragma unroll
    for (int k = 0; k < 5; ++k) {
      half4 h = *(const half4*)(xbp + (oy + u) * XST + ox0 + k * 4);
#pragma unroll
      for (int e = 0; e < 4; ++e) xr[k * 4 + e] = (float)h[e];
    }
    float zc[14];
    {
      half8 z0 = *(const half8*)(zbp + u * 16);
      half8 z1 = *(const half8*)(zbp + u * 16 + 8);
#pragma unroll
      for (int e = 0; e < 8; ++e) zc[e] = (float)z0[e];
#pragma unroll
      for (int e = 0; e < 6; ++e) zc[8 + e] = (float)z1[e];
    }
#pragma unroll
    for (int v = 0; v < 14; ++v)
#pragma unroll
      for (int j = 0; j < 4; ++j) acc[j] = fmaf(zc[v], xr[v + j], acc[j]);
  }

  if (ok) {
    float* op = out + (size_t)(ch0 + lc) * 289 + oy * 17;
#pragma unroll
    for (int j = 0; j < 4; ++j) {
      int ox = ox0 + j;
      if (ox < 17) op[ox] = acc[j];
    }
  }
}

extern "C" void kernel_launch(void* const* d_in, const int* in_sizes, int n_in,
                              void* d_out, int out_size, void* d_ws, size_t ws_size,
                              hipStream_t stream) {
  const float* z = (const float*)d_in[0];
  const float* x = (const float*)d_in[1];
  const float* w_z = (const float*)d_in[2];
  const float* w_x = (const float*)d_in[3];
  const float* gamma_z = (const float*)d_in[4];
  const float* beta_z = (const float*)d_in[5];
  const float* mean_z = (const float*)d_in[6];
  const float* var_z = (const float*)d_in[7];
  const float* gamma_x = (const float*)d_in[8];
  const float* beta_x = (const float*)d_in[9];
  const float* mean_x = (const float*)d_in[10];
  const float* var_x = (const float*)d_in[11];

  char* ws = (char*)d_ws;
  f16* xb = (f16*)(ws + OFF_XB);
  f16* zb = (f16*)(ws + OFF_ZB);
  f16* wxA = (f16*)(ws + OFF_WX);
  f16* wzA = (f16*)(ws + OFF_WZ);
  float* bnx = (float*)(ws + OFF_BNX);
  float* bnz = (float*)(ws + OFF_BNZ);
  f16* xfh = (f16*)(ws + OFF_XFH);
  f16* zfh = (f16*)(ws + OFF_ZFH);
  float* out = (float*)d_out;

  prep_all<<<16897, 256, 0, stream>>>(x, z, w_x, w_z,
                                      gamma_x, beta_x, mean_x, var_x,
                                      gamma_z, beta_z, mean_z, var_z,
                                      xb, zb, wxA, wzA, bnx, bnz);

  // 548 (pair) x 2 (mblk) tiles, padded to 1104 = 69*16 for the XCD permutation
  conv_gemm_u<<<1104, 256, 0, stream>>>(xb, zb, wxA, wzA, bnx, bnz, xfh, zfh);

  xcorr_dw3<<<(16384 + 2) / 3, 256, 0, stream>>>(zfh, xfh, out);
}